// Round 11
// baseline (1735.483 us; speedup 1.0000x reference)
//
#include <hip/hip_runtime.h>
#include <hip/hip_bf16.h>

typedef __attribute__((ext_vector_type(4))) float f32x4;
typedef __attribute__((ext_vector_type(4))) int   i32x4;
typedef __attribute__((ext_vector_type(8))) short s16x8;
typedef unsigned short ushort_t;

#define MDIM 8192
#define KDIM 4096
#define NDIM 16384
#define NKT  (KDIM / 32)        // 128 K-tiles of BK=32

static __device__ __forceinline__ short f2bf(float f) {
    __bf16 h = (__bf16)f;
    return __builtin_bit_cast(short, h);
}

static __device__ __forceinline__ void gload_lds16(const void* g, void* l) {
    __builtin_amdgcn_global_load_lds(
        (const __attribute__((address_space(1))) unsigned int*)g,
        (__attribute__((address_space(3))) unsigned int*)l,
        16, 0, 0);
}

// ---------------- convert kernels (memory-bound, vectorized) ----------------

__global__ __launch_bounds__(256)
void cvt_f32_bf16(const float* __restrict__ in, ushort_t* __restrict__ out, int n8) {
    for (int i = blockIdx.x * blockDim.x + threadIdx.x; i < n8;
         i += gridDim.x * blockDim.x) {
        f32x4 a = ((const f32x4*)in)[i * 2];
        f32x4 b = ((const f32x4*)in)[i * 2 + 1];
        s16x8 o;
        #pragma unroll
        for (int q = 0; q < 4; ++q) o[q] = f2bf(a[q]);
        #pragma unroll
        for (int q = 0; q < 4; ++q) o[4 + q] = f2bf(b[q]);
        ((s16x8*)out)[i] = o;
    }
}

__global__ __launch_bounds__(256)
void cvt_i32_bf16(const int* __restrict__ in, ushort_t* __restrict__ out, int n8) {
    for (int i = blockIdx.x * blockDim.x + threadIdx.x; i < n8;
         i += gridDim.x * blockDim.x) {
        i32x4 a = ((const i32x4*)in)[i * 2];
        i32x4 b = ((const i32x4*)in)[i * 2 + 1];
        s16x8 o;
        #pragma unroll
        for (int q = 0; q < 4; ++q) o[q] = f2bf((float)a[q]);   // |v|<=127: exact
        #pragma unroll
        for (int q = 0; q < 4; ++q) o[4 + q] = f2bf((float)b[q]);
        ((s16x8*)out)[i] = o;
    }
}

// ---------------- 256x128 bf16 GEMM, ring-3 LDS, 2 blocks/CU ---------------
// The lever: occupancy. 8 waves of 64x64 output (acc = 64 VGPR) keeps total
// VGPR <= 128 so __launch_bounds__(512,4) gives 4 waves/SIMD = 2 blocks/CU;
// LDS = 3 bufs x 24 KB = 72 KB/block (144 KB <= 160 KB for 2 blocks).
// Co-resident blocks are in separate barrier domains -> one block's MFMA
// window overlaps the other's LDS/stage window (m114/m97 mechanism; R2
// measured 12.8 TB/s inbound at 2 blocks/CU vs 7 at 1).
// Ring-3, lead-2 staging, trailing COUNTED vmcnt(3) (never 0):
//   iter it: read tile it from buf it%3 (8 ds_reads -> same-iter MFMA,
//   compiler-scheduled lgkm), stage tile it+2 -> buf (it+2)%3 (3 gloads),
//   16 MFMA, vmcnt(3) (drains tile it+1, staged a full iter ago), BAR.
// RAW: tile it drained at iter it-1's vmcnt(3)+BAR. WAR: buf (it+2)%3 holds
// tile it-1, read-complete before iter it-1's collective barrier.
// Per-buf layout: A[256 rows][64 B] @0 (16 KB, rows contiguous since call-2
// dest starts at 8192 = 128*64), B[128][64 B] @16384 (8 KB). Rows are 4
// slots of 16 B; phys slot = logical ^ ((row>>1)&3); swizzle applied on the
// GLOBAL source address, LDS dest linear (verbatim R6, conflict-verified).

#define BAR()   __builtin_amdgcn_s_barrier()
#define SB0()   __builtin_amdgcn_sched_barrier(0)

#define KTILE(IT, RB, WB)                                                      \
  {                                                                            \
    const char* rbuf = ldsc + (RB);                                            \
    char*       wbuf = ldsc + (WB);                                            \
    const size_t ko  = (size_t)(((IT) + 2) & (NKT - 1)) * 32;                  \
    s16x8 af[4], bq[4];                                                        \
    _Pragma("unroll")                                                          \
    for (int j = 0; j < 4; ++j) bq[j] = *(const s16x8*)(rbuf + boff[j]);       \
    _Pragma("unroll")                                                          \
    for (int i = 0; i < 4; ++i) af[i] = *(const s16x8*)(rbuf + aoff[i]);       \
    gload_lds16(pA0 + ko, wbuf + ldsw);                                        \
    gload_lds16(pA1 + ko, wbuf + 8192  + ldsw);                                \
    gload_lds16(pB0 + ko, wbuf + 16384 + ldsw);                                \
    _Pragma("unroll")                                                          \
    for (int i = 0; i < 4; ++i)                                                \
      _Pragma("unroll")                                                        \
      for (int j = 0; j < 4; ++j)                                              \
        acc[i][j] = __builtin_amdgcn_mfma_f32_16x16x32_bf16(                   \
            af[i], bq[j], acc[i][j], 0, 0, 0);                                 \
    asm volatile("s_waitcnt vmcnt(3)" ::: "memory");   /* counted, never 0 */  \
    BAR();                                                                     \
    SB0();                                                                     \
  }

__global__ __launch_bounds__(512, 4)
void sl_gemm_2b(const ushort_t* __restrict__ A, const ushort_t* __restrict__ Bw,
                const float* __restrict__ scale_p, const float* __restrict__ bias,
                float* __restrict__ Out)
{
    __shared__ char ldsbuf[73728];   // 3 bufs x (A 16 KB + B 8 KB)
    char* ldsc = ldsbuf;

    const int t    = threadIdx.x;
    const int lane = t & 63;
    const int wave = t >> 6;        // 0..7
    const int wr   = wave >> 1;     // 0..3 : 64 output rows each
    const int wc   = wave & 1;      // 0..1 : 64 output cols each

    // ---- tile mapping: XCD chunks of 512 = one 32tm x 16tn panel per chunk
    int bid = blockIdx.x;                       // 4096 blocks (32 tm x 128 tn)
    int swz = (bid & 7) * 512 + (bid >> 3);
    int panel = swz >> 9, inp = swz & 511;
    int tn = (panel << 4) + (inp >> 5);         // 0..127
    int tm = inp & 31;                          // 0..31
    const int m0 = tm << 8;
    const int n0 = tn << 7;

    // ---- staging geometry (verbatim R6 pattern): thread covers row
    //      (wave*16 + lane>>2) of a 128-row chunk, physical slot lane&3
    const int srow  = wave * 16 + (lane >> 2);            // 0..127
    const int sslot = lane & 3;
    const int sA    = sslot ^ ((srow >> 1) & 3);          // logical slot
    const ushort_t* pA0 = A  + (size_t)(m0 + srow) * KDIM + sA * 8;
    const ushort_t* pA1 = pA0 + (size_t)128 * KDIM;
    const ushort_t* pB0 = Bw + (size_t)(n0 + srow) * KDIM + sA * 8;
    const int ldsw = wave * 1024;                          // wave-uniform dest

    // ---- fragment read offsets (byte, buf-relative)
    const int fr = lane & 15;
    const int fs = lane >> 4;                              // 0..3
    int aoff[4], boff[4];
    #pragma unroll
    for (int i = 0; i < 4; ++i) {
        int ra = wr * 64 + i * 16 + fr;                    // 0..255
        aoff[i] = ra * 64 + ((fs ^ ((ra >> 1) & 3)) * 16);
    }
    #pragma unroll
    for (int j = 0; j < 4; ++j) {
        int rb = wc * 64 + j * 16 + fr;                    // 0..127
        boff[j] = 16384 + rb * 64 + ((fs ^ ((rb >> 1) & 3)) * 16);
    }

    f32x4 acc[4][4];
    #pragma unroll
    for (int i = 0; i < 4; ++i)
        #pragma unroll
        for (int j = 0; j < 4; ++j)
            acc[i][j] = (f32x4){0.f, 0.f, 0.f, 0.f};

    // ---- prologue: stage tiles 0,1 -> bufs 0,1 (3 calls each)
    #pragma unroll
    for (int kt = 0; kt < 2; ++kt) {
        const size_t ko = (size_t)kt * 32;
        char* b = ldsc + kt * 24576;
        gload_lds16(pA0 + ko, b + ldsw);
        gload_lds16(pA1 + ko, b + 8192  + ldsw);
        gload_lds16(pB0 + ko, b + 16384 + ldsw);
    }
    asm volatile("s_waitcnt vmcnt(3)" ::: "memory");   // tile 0 landed
    BAR();
    SB0();

    // ring period 3: iter it reads buf it%3, writes buf (it+2)%3
    for (int it = 0; it < 126; it += 3) {
        KTILE(it + 0, 0 * 24576, 2 * 24576);
        KTILE(it + 1, 1 * 24576, 0 * 24576);
        KTILE(it + 2, 2 * 24576, 1 * 24576);
    }
    KTILE(126, 0 * 24576, 2 * 24576);   // stages tile 0 again (identical bytes)
    KTILE(127, 1 * 24576, 0 * 24576);   // stages tile 1 again (identical bytes)

    // ---- epilogue: D col = lane&15, row = fs*4 + q; scale + bias
    const float scale = scale_p[0];
    #pragma unroll
    for (int j = 0; j < 4; ++j) {
        const int c   = n0 + wc * 64 + j * 16 + fr;
        const float bj = bias[c];
        #pragma unroll
        for (int i = 0; i < 4; ++i) {
            const int r0 = m0 + wr * 64 + i * 16 + fs * 4;
            float* op = Out + (size_t)r0 * NDIM + c;
            #pragma unroll
            for (int q = 0; q < 4; ++q)
                op[(size_t)q * NDIM] = acc[i][j][q] * scale + bj;
        }
    }
}

// ---------------- fallback (fp32 direct, no workspace) ----------------

__global__ __launch_bounds__(256, 2)
void sl_gemm_fb(const float* __restrict__ X, const int* __restrict__ Wq,
                const float* __restrict__ scale_p, const float* __restrict__ bias,
                float* __restrict__ Out)
{
    __shared__ s16x8 As[128 * 4];
    __shared__ s16x8 Bs[128 * 4];

    const int t    = threadIdx.x;
    const int lane = t & 63;
    const int wave = t >> 6;
    const int wr   = wave >> 1;
    const int wc   = wave & 1;

    int bid = blockIdx.x;
    int swz = (bid & 7) * 1024 + (bid >> 3);
    int panel   = swz >> 10;
    int inpanel = swz & 1023;
    int tn = (panel << 4) + (inpanel >> 6);
    int tm = inpanel & 63;
    const int m0 = tm << 7;
    const int n0 = tn << 7;

    const int srow  = t >> 1;
    const int shalf = t & 1;
    const float* Xp = X  + (size_t)(m0 + srow) * KDIM + shalf * 16;
    const int*   Wp = Wq + (size_t)(n0 + srow) * KDIM + shalf * 16;

    f32x4 acc[4][4];
    #pragma unroll
    for (int i = 0; i < 4; ++i)
        #pragma unroll
        for (int j = 0; j < 4; ++j)
            acc[i][j] = (f32x4){0.f, 0.f, 0.f, 0.f};

    const int fr = lane & 15;
    const int fs = lane >> 4;

    f32x4 ar[4];
    i32x4 br[4];
    #pragma unroll
    for (int p = 0; p < 4; ++p) {
        ar[p] = *(const f32x4*)(Xp + p * 4);
        br[p] = *(const i32x4*)(Wp + p * 4);
    }

    const int wbase = srow * 4;
    const int wswz  = (srow >> 1) & 3;
    const int ws0   = (shalf * 2)     ^ wswz;
    const int ws1   = (shalf * 2 + 1) ^ wswz;

    for (int kt = 0; kt < KDIM / 32; ++kt) {
        __syncthreads();
        {
            s16x8 v0, v1;
            #pragma unroll
            for (int q = 0; q < 8; ++q) v0[q] = f2bf(ar[q >> 2][q & 3]);
            #pragma unroll
            for (int q = 0; q < 8; ++q) v1[q] = f2bf(ar[2 + (q >> 2)][q & 3]);
            As[wbase + ws0] = v0;
            As[wbase + ws1] = v1;
            s16x8 u0, u1;
            #pragma unroll
            for (int q = 0; q < 8; ++q) u0[q] = f2bf((float)br[q >> 2][q & 3]);
            #pragma unroll
            for (int q = 0; q < 8; ++q) u1[q] = f2bf((float)br[2 + (q >> 2)][q & 3]);
            Bs[wbase + ws0] = u0;
            Bs[wbase + ws1] = u1;
        }
        __syncthreads();

        if (kt + 1 < KDIM / 32) {
            const float* Xn = Xp + (size_t)(kt + 1) * 32;
            const int*   Wn = Wp + (size_t)(kt + 1) * 32;
            #pragma unroll
            for (int p = 0; p < 4; ++p) {
                ar[p] = *(const f32x4*)(Xn + p * 4);
                br[p] = *(const i32x4*)(Wn + p * 4);
            }
        }

        s16x8 af[4], bq[4];
        #pragma unroll
        for (int i = 0; i < 4; ++i) {
            int row = wr * 64 + i * 16 + fr;
            af[i] = As[row * 4 + (fs ^ ((row >> 1) & 3))];
        }
        #pragma unroll
        for (int j = 0; j < 4; ++j) {
            int col = wc * 64 + j * 16 + fr;
            bq[j] = Bs[col * 4 + (fs ^ ((col >> 1) & 3))];
        }
        #pragma unroll
        for (int i = 0; i < 4; ++i)
            #pragma unroll
            for (int j = 0; j < 4; ++j)
                acc[i][j] = __builtin_amdgcn_mfma_f32_16x16x32_bf16(
                    af[i], bq[j], acc[i][j], 0, 0, 0);
    }

    const float scale = scale_p[0];
    #pragma unroll
    for (int j = 0; j < 4; ++j) {
        const int c  = n0 + wc * 64 + j * 16 + fr;
        const float bj = bias[c];
        #pragma unroll
        for (int i = 0; i < 4; ++i) {
            const int r0 = m0 + wr * 64 + i * 16 + fs * 4;
            float* op = Out + (size_t)r0 * NDIM + c;
            #pragma unroll
            for (int q = 0; q < 4; ++q)
                op[(size_t)q * NDIM] = acc[i][j][q] * scale + bj;
        }
    }
}

extern "C" void kernel_launch(void* const* d_in, const int* in_sizes, int n_in,
                              void* d_out, int out_size, void* d_ws, size_t ws_size,
                              hipStream_t stream) {
    const float* X     = (const float*)d_in[0];
    const int*   Wq    = (const int*)d_in[1];   // int8 widened to int32 by harness
    const float* scale = (const float*)d_in[2];
    const float* bias  = (const float*)d_in[3];
    float*       Out   = (float*)d_out;

    const size_t xBytes = (size_t)MDIM * KDIM * 2;          // 67 MB
    const size_t wBytes = (size_t)NDIM * KDIM * 2;          // 134 MB
    if (ws_size >= xBytes + wBytes) {
        ushort_t* Xbf = (ushort_t*)d_ws;
        ushort_t* Wbf = (ushort_t*)((char*)d_ws + xBytes);
        hipLaunchKernelGGL(cvt_f32_bf16, dim3(2048), dim3(256), 0, stream,
                           X, Xbf, MDIM * KDIM / 8);
        hipLaunchKernelGGL(cvt_i32_bf16, dim3(2048), dim3(256), 0, stream,
                           Wq, Wbf, NDIM * KDIM / 8);
        hipLaunchKernelGGL(sl_gemm_2b, dim3(4096), dim3(512), 0, stream,
                           Xbf, Wbf, scale, bias, Out);
    } else {
        hipLaunchKernelGGL(sl_gemm_fb, dim3(8192), dim3(256), 0, stream,
                           X, Wq, scale, bias, Out);
    }
}

// Round 12
// 1130.285 us; speedup vs baseline: 1.5354x; 1.5354x over previous
//
#include <hip/hip_runtime.h>
#include <hip/hip_bf16.h>

typedef __attribute__((ext_vector_type(4))) float f32x4;
typedef __attribute__((ext_vector_type(4))) int   i32x4;
typedef __attribute__((ext_vector_type(8))) short s16x8;
typedef unsigned short ushort_t;

#define MDIM 8192
#define KDIM 4096
#define NDIM 16384
#define NKT  64                 // 64 K-tiles of 64 int8 elems

static __device__ __forceinline__ short f2bf(float f) {
    __bf16 h = (__bf16)f;
    return __builtin_bit_cast(short, h);
}

static __device__ __forceinline__ void gload_lds16(const void* g, void* l) {
    __builtin_amdgcn_global_load_lds(
        (const __attribute__((address_space(1))) unsigned int*)g,
        (__attribute__((address_space(3))) unsigned int*)l,
        16, 0, 0);
}

// ---------------- prep kernels ----------------

// X fp32 -> int8 with per-row symmetric scale (RNE). One block per row.
__global__ __launch_bounds__(256)
void quant_x(const float* __restrict__ X, char* __restrict__ Xq,
             float* __restrict__ sx)
{
    __shared__ float wmax[4];
    const int row = blockIdx.x;
    const float* xr = X + (size_t)row * KDIM;
    const int t = threadIdx.x;
    f32x4 v[4];
    #pragma unroll
    for (int p = 0; p < 4; ++p) v[p] = ((const f32x4*)xr)[t * 4 + p];
    float m = 0.f;
    #pragma unroll
    for (int p = 0; p < 4; ++p)
        #pragma unroll
        for (int q = 0; q < 4; ++q)
            m = fmaxf(m, fabsf(v[p][q]));
    #pragma unroll
    for (int off = 32; off >= 1; off >>= 1)
        m = fmaxf(m, __shfl_xor(m, off));
    if ((t & 63) == 0) wmax[t >> 6] = m;
    __syncthreads();
    m = fmaxf(fmaxf(wmax[0], wmax[1]), fmaxf(wmax[2], wmax[3]));
    const float inv = 127.0f / fmaxf(m, 1e-30f);
    if (t == 0) sx[row] = m * (1.0f / 127.0f);
    int pk[4];
    #pragma unroll
    for (int p = 0; p < 4; ++p) {
        int q0 = min(127, max(-127, __float2int_rn(v[p][0] * inv)));
        int q1 = min(127, max(-127, __float2int_rn(v[p][1] * inv)));
        int q2 = min(127, max(-127, __float2int_rn(v[p][2] * inv)));
        int q3 = min(127, max(-127, __float2int_rn(v[p][3] * inv)));
        pk[p] = (q0 & 255) | ((q1 & 255) << 8) | ((q2 & 255) << 16) | ((q3 & 255) << 24);
    }
    ((i32x4*)(Xq + (size_t)row * KDIM))[t] = *(i32x4*)pk;
}

// W int32 (values in [-127,127]) -> int8 pack, 16 els/thread/iter
__global__ __launch_bounds__(256)
void pack_w(const int* __restrict__ in, char* __restrict__ out, int n16)
{
    for (int i = blockIdx.x * blockDim.x + threadIdx.x; i < n16;
         i += gridDim.x * blockDim.x) {
        int pk[4];
        #pragma unroll
        for (int p = 0; p < 4; ++p) {
            i32x4 a = ((const i32x4*)in)[i * 4 + p];
            pk[p] = (a[0] & 255) | ((a[1] & 255) << 8) |
                    ((a[2] & 255) << 16) | ((a[3] & 255) << 24);
        }
        ((i32x4*)out)[i] = *(i32x4*)pk;
    }
}

// ---------------- 256x256 int8 GEMM, ring-4 LDS, cross-tile reg dbuf -------
// Structure = R6 verbatim (best measured; hazards verified), dtype = int8:
//   K-tile = 64 int8 elems; rows are 64 B = 4 slots of 16 B (16 k-els each);
//   phys slot = logical ^ ((row>>1)&3); swizzle on the GLOBAL source addr,
//   LDS dest linear. Byte geometry identical to the bf16 version.
//   buf (it+1)&3 : 12 ds_reads into R_next (tile it+1)
//   buf (it+3)&3 : staged with tile it+3 (WAR-safe via trailing barrier)
//   trailing {vmcnt(4); s_barrier; sched_barrier(0)} per K-tile, never 0.
// mfma_i32_16x16x64_i8: A/B = 4 VGPR (16 int8), C/D = 4 i32 (exact accum).
// A/B share the same per-lane k-packing -> any internal k-permutation
// cancels in the dot product.

#define BAR()   __builtin_amdgcn_s_barrier()
#define SB0()   __builtin_amdgcn_sched_barrier(0)
#define PRIO(N) __builtin_amdgcn_s_setprio(N)

#define KTILE(CA, CB, NA, NB, IT, RB, WB)                                      \
  {                                                                            \
    const char* rbuf = ldsc + (RB);                                            \
    char*       wbuf = ldsc + (WB);                                            \
    const size_t ko  = (size_t)(((IT) + 3) & (NKT - 1)) * 64;                  \
    _Pragma("unroll")                                                          \
    for (int j = 0; j < 4; ++j) NB[j] = *(const i32x4*)(rbuf + boff[j]);       \
    _Pragma("unroll")                                                          \
    for (int i = 0; i < 4; ++i) NA[i] = *(const i32x4*)(rbuf + aoff[i]);       \
    gload_lds16(pA0 + ko, wbuf + ldsw);                                        \
    gload_lds16(pA1 + ko, wbuf + 8192 + ldsw);                                 \
    SB0();                                                                     \
    PRIO(1);                                                                   \
    _Pragma("unroll")                                                          \
    for (int m = 0; m < 4; ++m)                                                \
      _Pragma("unroll")                                                        \
      for (int nn = 0; nn < 4; ++nn)                                           \
        acc[m][nn] = __builtin_amdgcn_mfma_i32_16x16x64_i8(                    \
            CA[m], CB[nn], acc[m][nn], 0, 0, 0);                               \
    PRIO(0);                                                                   \
    _Pragma("unroll")                                                          \
    for (int i = 4; i < 8; ++i) NA[i] = *(const i32x4*)(rbuf + aoff[i]);       \
    gload_lds16(pB0 + ko, wbuf + 16384 + ldsw);                                \
    gload_lds16(pB1 + ko, wbuf + 24576 + ldsw);                                \
    SB0();                                                                     \
    PRIO(1);                                                                   \
    _Pragma("unroll")                                                          \
    for (int m = 4; m < 8; ++m)                                                \
      _Pragma("unroll")                                                        \
      for (int nn = 0; nn < 4; ++nn)                                           \
        acc[m][nn] = __builtin_amdgcn_mfma_i32_16x16x64_i8(                    \
            CA[m], CB[nn], acc[m][nn], 0, 0, 0);                               \
    PRIO(0);                                                                   \
    asm volatile("s_waitcnt vmcnt(4)" ::: "memory");                           \
    BAR();                                                                     \
    SB0();                                                                     \
  }

__global__ __launch_bounds__(512, 2)
void sl_gemm_i8(const char* __restrict__ A, const char* __restrict__ Bw,
                const float* __restrict__ sx,
                const float* __restrict__ scale_p, const float* __restrict__ bias,
                float* __restrict__ Out)
{
    __shared__ char ldsbuf[131072];   // 4 bufs x (A 16 KB + B 16 KB)
    char* ldsc = ldsbuf;

    const int t    = threadIdx.x;
    const int lane = t & 63;
    const int wave = t >> 6;        // 0..7
    const int wr   = wave >> 2;     // 0..1 : 128 output rows each
    const int wc   = wave & 3;      // 0..3 : 64  output cols each

    // ---- tile mapping: XCD chunks of 256, then 16-tn panels, tm fastest
    int bid = blockIdx.x;                       // 2048 blocks (32 tm x 64 tn)
    int swz = (bid & 7) * 256 + (bid >> 3);
    int panel = swz >> 9, inp = swz & 511;
    int tn = (panel << 4) + (inp >> 5);
    int tm = inp & 31;
    const int m0 = tm << 8;
    const int n0 = tn << 8;

    // ---- staging geometry (R6 pattern, byte-identical): thread covers row
    //      (wave*16 + lane>>2) of a 128-row chunk, physical slot lane&3
    const int srow  = wave * 16 + (lane >> 2);            // 0..127
    const int sslot = lane & 3;
    const int sA    = sslot ^ ((srow >> 1) & 3);          // logical slot
    const char* pA0 = A  + (size_t)(m0 + srow) * KDIM + sA * 16;
    const char* pA1 = pA0 + (size_t)128 * KDIM;
    const char* pB0 = Bw + (size_t)(n0 + srow) * KDIM + sA * 16;
    const char* pB1 = pB0 + (size_t)128 * KDIM;
    const int ldsw = wave * 1024;                          // wave-uniform dest

    // ---- fragment read offsets (byte, buf-relative; R6 formulas verbatim)
    const int fr = lane & 15;
    const int fs = lane >> 4;                              // 0..3
    int aoff[8], boff[4];
    #pragma unroll
    for (int i = 0; i < 8; ++i) {
        int ra = wr * 128 + i * 16 + fr;
        aoff[i] = ra * 64 + ((fs ^ ((ra >> 1) & 3)) * 16);
    }
    #pragma unroll
    for (int j = 0; j < 4; ++j) {
        int rb = wc * 64 + j * 16 + fr;
        boff[j] = 16384 + rb * 64 + ((fs ^ ((rb >> 1) & 3)) * 16);
    }

    i32x4 acc[8][4];
    #pragma unroll
    for (int i = 0; i < 8; ++i)
        #pragma unroll
        for (int j = 0; j < 4; ++j)
            acc[i][j] = (i32x4){0, 0, 0, 0};

    // ---- prologue: stage tiles 0,1,2 -> bufs 0,1,2
    #pragma unroll
    for (int kt = 0; kt < 3; ++kt) {
        const size_t ko = (size_t)kt * 64;
        char* b = ldsc + kt * 32768;
        gload_lds16(pA0 + ko, b + ldsw);
        gload_lds16(pA1 + ko, b + 8192  + ldsw);
        gload_lds16(pB0 + ko, b + 16384 + ldsw);
        gload_lds16(pB1 + ko, b + 24576 + ldsw);
    }
    asm volatile("s_waitcnt vmcnt(4)" ::: "memory");   // tiles 0,1 landed
    BAR();
    SB0();

    // R_cur <- tile 0 fragments (buf 0)
    i32x4 FA[8], FB[4], GA[8], GB[4];
    #pragma unroll
    for (int i = 0; i < 8; ++i) FA[i] = *(const i32x4*)(ldsc + aoff[i]);
    #pragma unroll
    for (int j = 0; j < 4; ++j) FB[j] = *(const i32x4*)(ldsc + boff[j]);

    // ring positions mod 4 compile-time per unrolled slot:
    //   slot p: read buf (p+1)&3, write buf (p+3)&3
    for (int it = 0; it < NKT; it += 4) {
        KTILE(FA, FB, GA, GB, it + 0, 1 * 32768, 3 * 32768);
        KTILE(GA, GB, FA, FB, it + 1, 2 * 32768, 0 * 32768);
        KTILE(FA, FB, GA, GB, it + 2, 3 * 32768, 1 * 32768);
        KTILE(GA, GB, FA, FB, it + 3, 0 * 32768, 2 * 32768);
    }

    // ---- epilogue: D col = lane&15, row = fs*4 + q; per-row dequant + bias
    const float scale = scale_p[0];
    #pragma unroll
    for (int i = 0; i < 8; ++i) {
        const int r0 = m0 + wr * 128 + i * 16 + fs * 4;
        float s4[4];
        #pragma unroll
        for (int q = 0; q < 4; ++q) s4[q] = sx[r0 + q] * scale;
        #pragma unroll
        for (int j = 0; j < 4; ++j) {
            const int c   = n0 + wc * 64 + j * 16 + fr;
            const float bj = bias[c];
            float* op = Out + (size_t)r0 * NDIM + c;
            #pragma unroll
            for (int q = 0; q < 4; ++q)
                op[(size_t)q * NDIM] = (float)acc[i][j][q] * s4[q] + bj;
        }
    }
}

// ---------------- fallback (fp32 direct, no workspace) ----------------

__global__ __launch_bounds__(256, 2)
void sl_gemm_fb(const float* __restrict__ X, const int* __restrict__ Wq,
                const float* __restrict__ scale_p, const float* __restrict__ bias,
                float* __restrict__ Out)
{
    __shared__ s16x8 As[128 * 4];
    __shared__ s16x8 Bs[128 * 4];

    const int t    = threadIdx.x;
    const int lane = t & 63;
    const int wave = t >> 6;
    const int wr   = wave >> 1;
    const int wc   = wave & 1;

    int bid = blockIdx.x;
    int swz = (bid & 7) * 1024 + (bid >> 3);
    int panel   = swz >> 10;
    int inpanel = swz & 1023;
    int tn = (panel << 4) + (inpanel >> 6);
    int tm = inpanel & 63;
    const int m0 = tm << 7;
    const int n0 = tn << 7;

    const int srow  = t >> 1;
    const int shalf = t & 1;
    const float* Xp = X  + (size_t)(m0 + srow) * KDIM + shalf * 16;
    const int*   Wp = Wq + (size_t)(n0 + srow) * KDIM + shalf * 16;

    f32x4 acc[4][4];
    #pragma unroll
    for (int i = 0; i < 4; ++i)
        #pragma unroll
        for (int j = 0; j < 4; ++j)
            acc[i][j] = (f32x4){0.f, 0.f, 0.f, 0.f};

    const int fr = lane & 15;
    const int fs = lane >> 4;

    f32x4 ar[4];
    i32x4 br[4];
    #pragma unroll
    for (int p = 0; p < 4; ++p) {
        ar[p] = *(const f32x4*)(Xp + p * 4);
        br[p] = *(const i32x4*)(Wp + p * 4);
    }

    const int wbase = srow * 4;
    const int wswz  = (srow >> 1) & 3;
    const int ws0   = (shalf * 2)     ^ wswz;
    const int ws1   = (shalf * 2 + 1) ^ wswz;

    for (int kt = 0; kt < KDIM / 32; ++kt) {
        __syncthreads();
        {
            s16x8 v0, v1;
            #pragma unroll
            for (int q = 0; q < 8; ++q) v0[q] = f2bf(ar[q >> 2][q & 3]);
            #pragma unroll
            for (int q = 0; q < 8; ++q) v1[q] = f2bf(ar[2 + (q >> 2)][q & 3]);
            As[wbase + ws0] = v0;
            As[wbase + ws1] = v1;
            s16x8 u0, u1;
            #pragma unroll
            for (int q = 0; q < 8; ++q) u0[q] = f2bf((float)br[q >> 2][q & 3]);
            #pragma unroll
            for (int q = 0; q < 8; ++q) u1[q] = f2bf((float)br[2 + (q >> 2)][q & 3]);
            Bs[wbase + ws0] = u0;
            Bs[wbase + ws1] = u1;
        }
        __syncthreads();

        if (kt + 1 < KDIM / 32) {
            const float* Xn = Xp + (size_t)(kt + 1) * 32;
            const int*   Wn = Wp + (size_t)(kt + 1) * 32;
            #pragma unroll
            for (int p = 0; p < 4; ++p) {
                ar[p] = *(const f32x4*)(Xn + p * 4);
                br[p] = *(const i32x4*)(Wn + p * 4);
            }
        }

        s16x8 af[4], bq[4];
        #pragma unroll
        for (int i = 0; i < 4; ++i) {
            int row = wr * 64 + i * 16 + fr;
            af[i] = As[row * 4 + (fs ^ ((row >> 1) & 3))];
        }
        #pragma unroll
        for (int j = 0; j < 4; ++j) {
            int col = wc * 64 + j * 16 + fr;
            bq[j] = Bs[col * 4 + (fs ^ ((col >> 1) & 3))];
        }
        #pragma unroll
        for (int i = 0; i < 4; ++i)
            #pragma unroll
            for (int j = 0; j < 4; ++j)
                acc[i][j] = __builtin_amdgcn_mfma_f32_16x16x32_bf16(
                    af[i], bq[j], acc[i][j], 0, 0, 0);
    }

    const float scale = scale_p[0];
    #pragma unroll
    for (int j = 0; j < 4; ++j) {
        const int c  = n0 + wc * 64 + j * 16 + fr;
        const float bj = bias[c];
        #pragma unroll
        for (int i = 0; i < 4; ++i) {
            const int r0 = m0 + wr * 64 + i * 16 + fs * 4;
            float* op = Out + (size_t)r0 * NDIM + c;
            #pragma unroll
            for (int q = 0; q < 4; ++q)
                op[(size_t)q * NDIM] = acc[i][j][q] * scale + bj;
        }
    }
}

extern "C" void kernel_launch(void* const* d_in, const int* in_sizes, int n_in,
                              void* d_out, int out_size, void* d_ws, size_t ws_size,
                              hipStream_t stream) {
    const float* X     = (const float*)d_in[0];
    const int*   Wq    = (const int*)d_in[1];   // int8 widened to int32 by harness
    const float* scale = (const float*)d_in[2];
    const float* bias  = (const float*)d_in[3];
    float*       Out   = (float*)d_out;

    const size_t xqB = (size_t)MDIM * KDIM;          // 33.5 MB
    const size_t wqB = (size_t)NDIM * KDIM;          // 67 MB
    const size_t sxB = (size_t)MDIM * sizeof(float); // 32 KB
    if (ws_size >= xqB + wqB + sxB) {
        char*  Xq  = (char*)d_ws;
        char*  Wq8 = (char*)d_ws + xqB;
        float* sx  = (float*)((char*)d_ws + xqB + wqB);
        hipLaunchKernelGGL(quant_x, dim3(MDIM), dim3(256), 0, stream, X, Xq, sx);
        hipLaunchKernelGGL(pack_w, dim3(2048), dim3(256), 0, stream,
                           Wq, Wq8, NDIM * KDIM / 16);
        hipLaunchKernelGGL(sl_gemm_i8, dim3(2048), dim3(512), 0, stream,
                           Xq, Wq8, sx, scale, bias, Out);
    } else {
        hipLaunchKernelGGL(sl_gemm_fb, dim3(8192), dim3(256), 0, stream,
                           X, Wq, scale, bias, Out);
    }
}

// Round 13
// 892.615 us; speedup vs baseline: 1.9443x; 1.2663x over previous
//
#include <hip/hip_runtime.h>
#include <hip/hip_bf16.h>

typedef __attribute__((ext_vector_type(4))) float f32x4;
typedef __attribute__((ext_vector_type(4))) int   i32x4;
typedef __attribute__((ext_vector_type(8))) short s16x8;
typedef unsigned short ushort_t;

#define MDIM 8192
#define KDIM 4096
#define NDIM 16384
#define NKT  64                 // 64 K-tiles of 64 int8 elems

static __device__ __forceinline__ short f2bf(float f) {
    __bf16 h = (__bf16)f;
    return __builtin_bit_cast(short, h);
}

static __device__ __forceinline__ void gload_lds16(const void* g, void* l) {
    __builtin_amdgcn_global_load_lds(
        (const __attribute__((address_space(1))) unsigned int*)g,
        (__attribute__((address_space(3))) unsigned int*)l,
        16, 0, 0);
}

// ---------------- prep kernels ----------------

// X fp32 -> int8 with per-row symmetric scale (RNE). One block per row.
__global__ __launch_bounds__(256)
void quant_x(const float* __restrict__ X, char* __restrict__ Xq,
             float* __restrict__ sx)
{
    __shared__ float wmax[4];
    const int row = blockIdx.x;
    const float* xr = X + (size_t)row * KDIM;
    const int t = threadIdx.x;
    f32x4 v[4];
    #pragma unroll
    for (int p = 0; p < 4; ++p) v[p] = ((const f32x4*)xr)[t * 4 + p];
    float m = 0.f;
    #pragma unroll
    for (int p = 0; p < 4; ++p)
        #pragma unroll
        for (int q = 0; q < 4; ++q)
            m = fmaxf(m, fabsf(v[p][q]));
    #pragma unroll
    for (int off = 32; off >= 1; off >>= 1)
        m = fmaxf(m, __shfl_xor(m, off));
    if ((t & 63) == 0) wmax[t >> 6] = m;
    __syncthreads();
    m = fmaxf(fmaxf(wmax[0], wmax[1]), fmaxf(wmax[2], wmax[3]));
    const float inv = 127.0f / fmaxf(m, 1e-30f);
    if (t == 0) sx[row] = m * (1.0f / 127.0f);
    int pk[4];
    #pragma unroll
    for (int p = 0; p < 4; ++p) {
        int q0 = min(127, max(-127, __float2int_rn(v[p][0] * inv)));
        int q1 = min(127, max(-127, __float2int_rn(v[p][1] * inv)));
        int q2 = min(127, max(-127, __float2int_rn(v[p][2] * inv)));
        int q3 = min(127, max(-127, __float2int_rn(v[p][3] * inv)));
        pk[p] = (q0 & 255) | ((q1 & 255) << 8) | ((q2 & 255) << 16) | ((q3 & 255) << 24);
    }
    ((i32x4*)(Xq + (size_t)row * KDIM))[t] = *(i32x4*)pk;
}

// W int32 (values in [-127,127]) -> int8 pack, 16 els/thread/iter
__global__ __launch_bounds__(256)
void pack_w(const int* __restrict__ in, char* __restrict__ out, int n16)
{
    for (int i = blockIdx.x * blockDim.x + threadIdx.x; i < n16;
         i += gridDim.x * blockDim.x) {
        int pk[4];
        #pragma unroll
        for (int p = 0; p < 4; ++p) {
            i32x4 a = ((const i32x4*)in)[i * 4 + p];
            pk[p] = (a[0] & 255) | ((a[1] & 255) << 8) |
                    ((a[2] & 255) << 16) | ((a[3] & 255) << 24);
        }
        ((i32x4*)out)[i] = *(i32x4*)pk;
    }
}

// ---------------- 256x256 int8 GEMM, ring-4 LDS, cross-tile reg dbuf -------
// Kernel body = R12 verbatim (passed, absmax 3.0; hazards verified).
// R13 change: block->tile mapping only. XCD x (bid&7) STATICALLY owns
// A-rows [x*1024, x*1024+1024) -- a 4 MB i8 slab that is L2-resident for
// the whole kernel (timing-independent: every block on XCD x has
// tm in [4x, 4x+4)). The 32 CUs of an XCD sweep tn together (concurrent
// blocks share 8 B-panels). L2-miss demand drops ~2.2 GB -> ~0.6 GB,
// unblocking the ~2 TB/s L2-miss-path pace that has governed every round.

#define BAR()   __builtin_amdgcn_s_barrier()
#define SB0()   __builtin_amdgcn_sched_barrier(0)
#define PRIO(N) __builtin_amdgcn_s_setprio(N)

#define KTILE(CA, CB, NA, NB, IT, RB, WB)                                      \
  {                                                                            \
    const char* rbuf = ldsc + (RB);                                            \
    char*       wbuf = ldsc + (WB);                                            \
    const size_t ko  = (size_t)(((IT) + 3) & (NKT - 1)) * 64;                  \
    _Pragma("unroll")                                                          \
    for (int j = 0; j < 4; ++j) NB[j] = *(const i32x4*)(rbuf + boff[j]);       \
    _Pragma("unroll")                                                          \
    for (int i = 0; i < 4; ++i) NA[i] = *(const i32x4*)(rbuf + aoff[i]);       \
    gload_lds16(pA0 + ko, wbuf + ldsw);                                        \
    gload_lds16(pA1 + ko, wbuf + 8192 + ldsw);                                 \
    SB0();                                                                     \
    PRIO(1);                                                                   \
    _Pragma("unroll")                                                          \
    for (int m = 0; m < 4; ++m)                                                \
      _Pragma("unroll")                                                        \
      for (int nn = 0; nn < 4; ++nn)                                           \
        acc[m][nn] = __builtin_amdgcn_mfma_i32_16x16x64_i8(                    \
            CA[m], CB[nn], acc[m][nn], 0, 0, 0);                               \
    PRIO(0);                                                                   \
    _Pragma("unroll")                                                          \
    for (int i = 4; i < 8; ++i) NA[i] = *(const i32x4*)(rbuf + aoff[i]);       \
    gload_lds16(pB0 + ko, wbuf + 16384 + ldsw);                                \
    gload_lds16(pB1 + ko, wbuf + 24576 + ldsw);                                \
    SB0();                                                                     \
    PRIO(1);                                                                   \
    _Pragma("unroll")                                                          \
    for (int m = 4; m < 8; ++m)                                                \
      _Pragma("unroll")                                                        \
      for (int nn = 0; nn < 4; ++nn)                                           \
        acc[m][nn] = __builtin_amdgcn_mfma_i32_16x16x64_i8(                    \
            CA[m], CB[nn], acc[m][nn], 0, 0, 0);                               \
    PRIO(0);                                                                   \
    asm volatile("s_waitcnt vmcnt(4)" ::: "memory");                           \
    BAR();                                                                     \
    SB0();                                                                     \
  }

__global__ __launch_bounds__(512, 2)
void sl_gemm_i8(const char* __restrict__ A, const char* __restrict__ Bw,
                const float* __restrict__ sx,
                const float* __restrict__ scale_p, const float* __restrict__ bias,
                float* __restrict__ Out)
{
    __shared__ char ldsbuf[131072];   // 4 bufs x (A 16 KB + B 16 KB)
    char* ldsc = ldsbuf;

    const int t    = threadIdx.x;
    const int lane = t & 63;
    const int wave = t >> 6;        // 0..7
    const int wr   = wave >> 2;     // 0..1 : 128 output rows each
    const int wc   = wave & 3;      // 0..3 : 64  output cols each

    // ---- tile mapping (R13): XCD-static A-slab
    //   XCD x = bid&7 owns tm in [4x, 4x+4)  (A rows [x*1024, x*1024+1024),
    //   4 MB i8 -> L2-resident). Concurrent blocks of an XCD (r = bid>>3
    //   contiguous) share tn-panels: tn advances every 4 blocks.
    int bid = blockIdx.x;                       // 2048 blocks (32 tm x 64 tn)
    int tm = ((bid & 7) << 2) + ((bid >> 3) & 3);
    int tn = bid >> 5;
    const int m0 = tm << 8;
    const int n0 = tn << 8;

    // ---- staging geometry (R6/R12 pattern, byte-identical): thread covers
    //      row (wave*16 + lane>>2) of a 128-row chunk, physical slot lane&3
    const int srow  = wave * 16 + (lane >> 2);            // 0..127
    const int sslot = lane & 3;
    const int sA    = sslot ^ ((srow >> 1) & 3);          // logical slot
    const char* pA0 = A  + (size_t)(m0 + srow) * KDIM + sA * 16;
    const char* pA1 = pA0 + (size_t)128 * KDIM;
    const char* pB0 = Bw + (size_t)(n0 + srow) * KDIM + sA * 16;
    const char* pB1 = pB0 + (size_t)128 * KDIM;
    const int ldsw = wave * 1024;                          // wave-uniform dest

    // ---- fragment read offsets (byte, buf-relative; R6/R12 verbatim)
    const int fr = lane & 15;
    const int fs = lane >> 4;                              // 0..3
    int aoff[8], boff[4];
    #pragma unroll
    for (int i = 0; i < 8; ++i) {
        int ra = wr * 128 + i * 16 + fr;
        aoff[i] = ra * 64 + ((fs ^ ((ra >> 1) & 3)) * 16);
    }
    #pragma unroll
    for (int j = 0; j < 4; ++j) {
        int rb = wc * 64 + j * 16 + fr;
        boff[j] = 16384 + rb * 64 + ((fs ^ ((rb >> 1) & 3)) * 16);
    }

    i32x4 acc[8][4];
    #pragma unroll
    for (int i = 0; i < 8; ++i)
        #pragma unroll
        for (int j = 0; j < 4; ++j)
            acc[i][j] = (i32x4){0, 0, 0, 0};

    // ---- prologue: stage tiles 0,1,2 -> bufs 0,1,2
    #pragma unroll
    for (int kt = 0; kt < 3; ++kt) {
        const size_t ko = (size_t)kt * 64;
        char* b = ldsc + kt * 32768;
        gload_lds16(pA0 + ko, b + ldsw);
        gload_lds16(pA1 + ko, b + 8192  + ldsw);
        gload_lds16(pB0 + ko, b + 16384 + ldsw);
        gload_lds16(pB1 + ko, b + 24576 + ldsw);
    }
    asm volatile("s_waitcnt vmcnt(4)" ::: "memory");   // tiles 0,1 landed
    BAR();
    SB0();

    // R_cur <- tile 0 fragments (buf 0)
    i32x4 FA[8], FB[4], GA[8], GB[4];
    #pragma unroll
    for (int i = 0; i < 8; ++i) FA[i] = *(const i32x4*)(ldsc + aoff[i]);
    #pragma unroll
    for (int j = 0; j < 4; ++j) FB[j] = *(const i32x4*)(ldsc + boff[j]);

    // ring positions mod 4 compile-time per unrolled slot:
    //   slot p: read buf (p+1)&3, write buf (p+3)&3
    for (int it = 0; it < NKT; it += 4) {
        KTILE(FA, FB, GA, GB, it + 0, 1 * 32768, 3 * 32768);
        KTILE(GA, GB, FA, FB, it + 1, 2 * 32768, 0 * 32768);
        KTILE(FA, FB, GA, GB, it + 2, 3 * 32768, 1 * 32768);
        KTILE(GA, GB, FA, FB, it + 3, 0 * 32768, 2 * 32768);
    }

    // ---- epilogue: D col = lane&15, row = fs*4 + q; per-row dequant + bias
    const float scale = scale_p[0];
    #pragma unroll
    for (int i = 0; i < 8; ++i) {
        const int r0 = m0 + wr * 128 + i * 16 + fs * 4;
        float s4[4];
        #pragma unroll
        for (int q = 0; q < 4; ++q) s4[q] = sx[r0 + q] * scale;
        #pragma unroll
        for (int j = 0; j < 4; ++j) {
            const int c   = n0 + wc * 64 + j * 16 + fr;
            const float bj = bias[c];
            float* op = Out + (size_t)r0 * NDIM + c;
            #pragma unroll
            for (int q = 0; q < 4; ++q)
                op[(size_t)q * NDIM] = (float)acc[i][j][q] * s4[q] + bj;
        }
    }
}

// ---------------- fallback (fp32 direct, no workspace) ----------------

__global__ __launch_bounds__(256, 2)
void sl_gemm_fb(const float* __restrict__ X, const int* __restrict__ Wq,
                const float* __restrict__ scale_p, const float* __restrict__ bias,
                float* __restrict__ Out)
{
    __shared__ s16x8 As[128 * 4];
    __shared__ s16x8 Bs[128 * 4];

    const int t    = threadIdx.x;
    const int lane = t & 63;
    const int wave = t >> 6;
    const int wr   = wave >> 1;
    const int wc   = wave & 1;

    int bid = blockIdx.x;
    int swz = (bid & 7) * 1024 + (bid >> 3);
    int panel   = swz >> 10;
    int inpanel = swz & 1023;
    int tn = (panel << 4) + (inpanel >> 6);
    int tm = inpanel & 63;
    const int m0 = tm << 7;
    const int n0 = tn << 7;

    const int srow  = t >> 1;
    const int shalf = t & 1;
    const float* Xp = X  + (size_t)(m0 + srow) * KDIM + shalf * 16;
    const int*   Wp = Wq + (size_t)(n0 + srow) * KDIM + shalf * 16;

    f32x4 acc[4][4];
    #pragma unroll
    for (int i = 0; i < 4; ++i)
        #pragma unroll
        for (int j = 0; j < 4; ++j)
            acc[i][j] = (f32x4){0.f, 0.f, 0.f, 0.f};

    const int fr = lane & 15;
    const int fs = lane >> 4;

    f32x4 ar[4];
    i32x4 br[4];
    #pragma unroll
    for (int p = 0; p < 4; ++p) {
        ar[p] = *(const f32x4*)(Xp + p * 4);
        br[p] = *(const i32x4*)(Wp + p * 4);
    }

    const int wbase = srow * 4;
    const int wswz  = (srow >> 1) & 3;
    const int ws0   = (shalf * 2)     ^ wswz;
    const int ws1   = (shalf * 2 + 1) ^ wswz;

    for (int kt = 0; kt < KDIM / 32; ++kt) {
        __syncthreads();
        {
            s16x8 v0, v1;
            #pragma unroll
            for (int q = 0; q < 8; ++q) v0[q] = f2bf(ar[q >> 2][q & 3]);
            #pragma unroll
            for (int q = 0; q < 8; ++q) v1[q] = f2bf(ar[2 + (q >> 2)][q & 3]);
            As[wbase + ws0] = v0;
            As[wbase + ws1] = v1;
            s16x8 u0, u1;
            #pragma unroll
            for (int q = 0; q < 8; ++q) u0[q] = f2bf((float)br[q >> 2][q & 3]);
            #pragma unroll
            for (int q = 0; q < 8; ++q) u1[q] = f2bf((float)br[2 + (q >> 2)][q & 3]);
            Bs[wbase + ws0] = u0;
            Bs[wbase + ws1] = u1;
        }
        __syncthreads();

        if (kt + 1 < KDIM / 32) {
            const float* Xn = Xp + (size_t)(kt + 1) * 32;
            const int*   Wn = Wp + (size_t)(kt + 1) * 32;
            #pragma unroll
            for (int p = 0; p < 4; ++p) {
                ar[p] = *(const f32x4*)(Xn + p * 4);
                br[p] = *(const i32x4*)(Wn + p * 4);
            }
        }

        s16x8 af[4], bq[4];
        #pragma unroll
        for (int i = 0; i < 4; ++i) {
            int row = wr * 64 + i * 16 + fr;
            af[i] = As[row * 4 + (fs ^ ((row >> 1) & 3))];
        }
        #pragma unroll
        for (int j = 0; j < 4; ++j) {
            int col = wc * 64 + j * 16 + fr;
            bq[j] = Bs[col * 4 + (fs ^ ((col >> 1) & 3))];
        }
        #pragma unroll
        for (int i = 0; i < 4; ++i)
            #pragma unroll
            for (int j = 0; j < 4; ++j)
                acc[i][j] = __builtin_amdgcn_mfma_f32_16x16x32_bf16(
                    af[i], bq[j], acc[i][j], 0, 0, 0);
    }

    const float scale = scale_p[0];
    #pragma unroll
    for (int j = 0; j < 4; ++j) {
        const int c  = n0 + wc * 64 + j * 16 + fr;
        const float bj = bias[c];
        #pragma unroll
        for (int i = 0; i < 4; ++i) {
            const int r0 = m0 + wr * 64 + i * 16 + fs * 4;
            float* op = Out + (size_t)r0 * NDIM + c;
            #pragma unroll
            for (int q = 0; q < 4; ++q)
                op[(size_t)q * NDIM] = acc[i][j][q] * scale + bj;
        }
    }
}

extern "C" void kernel_launch(void* const* d_in, const int* in_sizes, int n_in,
                              void* d_out, int out_size, void* d_ws, size_t ws_size,
                              hipStream_t stream) {
    const float* X     = (const float*)d_in[0];
    const int*   Wq    = (const int*)d_in[1];   // int8 widened to int32 by harness
    const float* scale = (const float*)d_in[2];
    const float* bias  = (const float*)d_in[3];
    float*       Out   = (float*)d_out;

    const size_t xqB = (size_t)MDIM * KDIM;          // 33.5 MB
    const size_t wqB = (size_t)NDIM * KDIM;          // 67 MB
    const size_t sxB = (size_t)MDIM * sizeof(float); // 32 KB
    if (ws_size >= xqB + wqB + sxB) {
        char*  Xq  = (char*)d_ws;
        char*  Wq8 = (char*)d_ws + xqB;
        float* sx  = (float*)((char*)d_ws + xqB + wqB);
        hipLaunchKernelGGL(quant_x, dim3(MDIM), dim3(256), 0, stream, X, Xq, sx);
        hipLaunchKernelGGL(pack_w, dim3(2048), dim3(256), 0, stream,
                           Wq, Wq8, NDIM * KDIM / 16);
        hipLaunchKernelGGL(sl_gemm_i8, dim3(2048), dim3(512), 0, stream,
                           Xq, Wq8, sx, scale, bias, Out);
    } else {
        hipLaunchKernelGGL(sl_gemm_fb, dim3(8192), dim3(256), 0, stream,
                           X, Wq, scale, bias, Out);
    }
}

// Round 14
// 839.081 us; speedup vs baseline: 2.0683x; 1.0638x over previous
//
#include <hip/hip_runtime.h>
#include <hip/hip_bf16.h>

typedef __attribute__((ext_vector_type(4))) float f32x4;
typedef __attribute__((ext_vector_type(4))) int   i32x4;
typedef __attribute__((ext_vector_type(8))) short s16x8;
typedef unsigned short ushort_t;

#define MDIM 8192
#define KDIM 4096
#define NDIM 16384
#define NKT  64                 // 64 K-tiles of 64 int8 elems

static __device__ __forceinline__ short f2bf(float f) {
    __bf16 h = (__bf16)f;
    return __builtin_bit_cast(short, h);
}

static __device__ __forceinline__ void gload_lds16(const void* g, void* l) {
    __builtin_amdgcn_global_load_lds(
        (const __attribute__((address_space(1))) unsigned int*)g,
        (__attribute__((address_space(3))) unsigned int*)l,
        16, 0, 0);
}

// ---------------- prep kernels ----------------

// X fp32 -> int8 with per-row symmetric scale (RNE). One block per row.
__global__ __launch_bounds__(256)
void quant_x(const float* __restrict__ X, char* __restrict__ Xq,
             float* __restrict__ sx)
{
    __shared__ float wmax[4];
    const int row = blockIdx.x;
    const float* xr = X + (size_t)row * KDIM;
    const int t = threadIdx.x;
    f32x4 v[4];
    #pragma unroll
    for (int p = 0; p < 4; ++p) v[p] = ((const f32x4*)xr)[t * 4 + p];
    float m = 0.f;
    #pragma unroll
    for (int p = 0; p < 4; ++p)
        #pragma unroll
        for (int q = 0; q < 4; ++q)
            m = fmaxf(m, fabsf(v[p][q]));
    #pragma unroll
    for (int off = 32; off >= 1; off >>= 1)
        m = fmaxf(m, __shfl_xor(m, off));
    if ((t & 63) == 0) wmax[t >> 6] = m;
    __syncthreads();
    m = fmaxf(fmaxf(wmax[0], wmax[1]), fmaxf(wmax[2], wmax[3]));
    const float inv = 127.0f / fmaxf(m, 1e-30f);
    if (t == 0) sx[row] = m * (1.0f / 127.0f);
    int pk[4];
    #pragma unroll
    for (int p = 0; p < 4; ++p) {
        int q0 = min(127, max(-127, __float2int_rn(v[p][0] * inv)));
        int q1 = min(127, max(-127, __float2int_rn(v[p][1] * inv)));
        int q2 = min(127, max(-127, __float2int_rn(v[p][2] * inv)));
        int q3 = min(127, max(-127, __float2int_rn(v[p][3] * inv)));
        pk[p] = (q0 & 255) | ((q1 & 255) << 8) | ((q2 & 255) << 16) | ((q3 & 255) << 24);
    }
    ((i32x4*)(Xq + (size_t)row * KDIM))[t] = *(i32x4*)pk;
}

// W int32 (values in [-127,127]) -> int8 pack, 16 els/thread/iter
__global__ __launch_bounds__(256)
void pack_w(const int* __restrict__ in, char* __restrict__ out, int n16)
{
    for (int i = blockIdx.x * blockDim.x + threadIdx.x; i < n16;
         i += gridDim.x * blockDim.x) {
        int pk[4];
        #pragma unroll
        for (int p = 0; p < 4; ++p) {
            i32x4 a = ((const i32x4*)in)[i * 4 + p];
            pk[p] = (a[0] & 255) | ((a[1] & 255) << 8) |
                    ((a[2] & 255) << 16) | ((a[3] & 255) << 24);
        }
        ((i32x4*)out)[i] = *(i32x4*)pk;
    }
}

// ---------------- 128x128 int8 GEMM, ring-3 LDS, 3 blocks/CU ---------------
// Combines the three proven levers:
//   (1) i8 MFMA (R12: 2x compute density, exact accum; absmax 3.0 ok)
//   (2) XCD-static A-slab (R13: XCD x owns A rows [x*1024,x*1024+1024),
//       4 MB i8, L2-resident; FETCH 1.34 -> 0.47 GB)
//   (3) multi-block co-residency (R2/m97 mechanism): 128^2 tile, 256 thr
//       (4 waves x 64x64 out, acc=64 AGPR), ring-3 x 16 KB = 48 KB LDS ->
//       3 blocks/CU; blocks are in separate barrier domains, so one block's
//       MFMA window overlaps another's LDS/stage window.
// Hazards = R11's verified ring-3 scheme: iter it reads buf it%3 (8 ds_reads,
// same-iter MFMA, compiler-scheduled lgkm), stages tile it+2 into buf
// (it+2)%3 (4 gload calls), trailing COUNTED vmcnt(4) (drains tile it+1,
// staged a full iter ago; never 0) + s_barrier.
// Byte geometry verbatim R6/R12: rows 64 B = 4 slots of 16 B; phys slot =
// logical ^ ((row>>1)&3); swizzle on the GLOBAL source addr, LDS dest linear.

#define BAR()   __builtin_amdgcn_s_barrier()
#define SB0()   __builtin_amdgcn_sched_barrier(0)

#define KTILE(IT, RB, WB)                                                      \
  {                                                                            \
    const char* rbuf = ldsc + (RB);                                            \
    char*       wbuf = ldsc + (WB);                                            \
    const size_t ko  = (size_t)(((IT) + 2) & (NKT - 1)) * 64;                  \
    i32x4 af[4], bq[4];                                                        \
    _Pragma("unroll")                                                          \
    for (int j = 0; j < 4; ++j) bq[j] = *(const i32x4*)(rbuf + boff[j]);       \
    _Pragma("unroll")                                                          \
    for (int i = 0; i < 4; ++i) af[i] = *(const i32x4*)(rbuf + aoff[i]);       \
    gload_lds16(pA0 + ko, wbuf + 0     + ldsw);                                \
    gload_lds16(pA1 + ko, wbuf + 4096  + ldsw);                                \
    gload_lds16(pB0 + ko, wbuf + 8192  + ldsw);                                \
    gload_lds16(pB1 + ko, wbuf + 12288 + ldsw);                                \
    _Pragma("unroll")                                                          \
    for (int i = 0; i < 4; ++i)                                                \
      _Pragma("unroll")                                                        \
      for (int j = 0; j < 4; ++j)                                              \
        acc[i][j] = __builtin_amdgcn_mfma_i32_16x16x64_i8(                     \
            af[i], bq[j], acc[i][j], 0, 0, 0);                                 \
    asm volatile("s_waitcnt vmcnt(4)" ::: "memory");   /* counted, never 0 */  \
    BAR();                                                                     \
    SB0();                                                                     \
  }

__global__ __launch_bounds__(256, 3)
void sl_gemm_i8s(const char* __restrict__ A, const char* __restrict__ Bw,
                 const float* __restrict__ sx,
                 const float* __restrict__ scale_p, const float* __restrict__ bias,
                 float* __restrict__ Out)
{
    __shared__ char ldsbuf[49152];   // 3 bufs x (A 8 KB + B 8 KB)
    char* ldsc = ldsbuf;

    const int t    = threadIdx.x;
    const int lane = t & 63;
    const int wave = t >> 6;        // 0..3
    const int wr   = wave >> 1;     // 0..1 : 64 output rows each
    const int wc   = wave & 1;      // 0..1 : 64 output cols each

    // ---- tile mapping: XCD-static A-slab. XCD x = bid&7 owns tm in
    //      [8x, 8x+8) (A rows [x*1024, x*1024+1024) = 4 MB i8, L2-resident).
    //      tm varies fastest among an XCD's concurrent blocks; tn advances
    //      every 64 blocks.
    int bid = blockIdx.x;                       // 8192 blocks (64 tm x 128 tn)
    int tm = ((bid & 7) << 3) + ((bid >> 3) & 7);
    int tn = bid >> 6;
    const int m0 = tm << 7;
    const int n0 = tn << 7;

    // ---- staging geometry: per gload call (4 KB = 64 rows), thread covers
    //      row c*64 + (t>>2), physical slot t&3; logical slot = phys ^
    //      ((row>>1)&3)  (row mod 8 == srow mod 8 since 64 | c*64)
    const int srow  = t >> 2;                             // 0..63
    const int sslot = t & 3;
    const int sA    = sslot ^ ((srow >> 1) & 3);
    const char* pA0 = A  + (size_t)(m0 + srow) * KDIM + sA * 16;
    const char* pA1 = pA0 + (size_t)64 * KDIM;
    const char* pB0 = Bw + (size_t)(n0 + srow) * KDIM + sA * 16;
    const char* pB1 = pB0 + (size_t)64 * KDIM;
    const int ldsw = wave * 1024;                          // wave-uniform dest

    // ---- fragment read offsets (byte, buf-relative; R6/R12 formulas)
    const int fr = lane & 15;
    const int fs = lane >> 4;                              // 0..3
    int aoff[4], boff[4];
    #pragma unroll
    for (int i = 0; i < 4; ++i) {
        int ra = wr * 64 + i * 16 + fr;                    // 0..127
        aoff[i] = ra * 64 + ((fs ^ ((ra >> 1) & 3)) * 16);
    }
    #pragma unroll
    for (int j = 0; j < 4; ++j) {
        int rb = wc * 64 + j * 16 + fr;                    // 0..127
        boff[j] = 8192 + rb * 64 + ((fs ^ ((rb >> 1) & 3)) * 16);
    }

    i32x4 acc[4][4];
    #pragma unroll
    for (int i = 0; i < 4; ++i)
        #pragma unroll
        for (int j = 0; j < 4; ++j)
            acc[i][j] = (i32x4){0, 0, 0, 0};

    // ---- prologue: stage tiles 0,1 -> bufs 0,1 (4 calls each)
    #pragma unroll
    for (int kt = 0; kt < 2; ++kt) {
        const size_t ko = (size_t)kt * 64;
        char* b = ldsc + kt * 16384;
        gload_lds16(pA0 + ko, b + 0     + ldsw);
        gload_lds16(pA1 + ko, b + 4096  + ldsw);
        gload_lds16(pB0 + ko, b + 8192  + ldsw);
        gload_lds16(pB1 + ko, b + 12288 + ldsw);
    }
    asm volatile("s_waitcnt vmcnt(4)" ::: "memory");   // tile 0 landed
    BAR();
    SB0();

    // ring period 3: iter it reads buf it%3, writes buf (it+2)%3
    for (int it = 0; it < 63; it += 3) {
        KTILE(it + 0, 0 * 16384, 2 * 16384);
        KTILE(it + 1, 1 * 16384, 0 * 16384);
        KTILE(it + 2, 2 * 16384, 1 * 16384);
    }
    KTILE(63, 0 * 16384, 2 * 16384);   // tail: re-stages tile 1 (same bytes)

    // ---- epilogue: D col = lane&15, row = fs*4 + q; per-row dequant + bias
    const float scale = scale_p[0];
    #pragma unroll
    for (int i = 0; i < 4; ++i) {
        const int r0 = m0 + wr * 64 + i * 16 + fs * 4;
        float s4[4];
        #pragma unroll
        for (int q = 0; q < 4; ++q) s4[q] = sx[r0 + q] * scale;
        #pragma unroll
        for (int j = 0; j < 4; ++j) {
            const int c   = n0 + wc * 64 + j * 16 + fr;
            const float bj = bias[c];
            float* op = Out + (size_t)r0 * NDIM + c;
            #pragma unroll
            for (int q = 0; q < 4; ++q)
                op[(size_t)q * NDIM] = (float)acc[i][j][q] * s4[q] + bj;
        }
    }
}

// ---------------- fallback (fp32 direct, no workspace) ----------------

__global__ __launch_bounds__(256, 2)
void sl_gemm_fb(const float* __restrict__ X, const int* __restrict__ Wq,
                const float* __restrict__ scale_p, const float* __restrict__ bias,
                float* __restrict__ Out)
{
    __shared__ s16x8 As[128 * 4];
    __shared__ s16x8 Bs[128 * 4];

    const int t    = threadIdx.x;
    const int lane = t & 63;
    const int wave = t >> 6;
    const int wr   = wave >> 1;
    const int wc   = wave & 1;

    int bid = blockIdx.x;
    int swz = (bid & 7) * 1024 + (bid >> 3);
    int panel   = swz >> 10;
    int inpanel = swz & 1023;
    int tn = (panel << 4) + (inpanel >> 6);
    int tm = inpanel & 63;
    const int m0 = tm << 7;
    const int n0 = tn << 7;

    const int srow  = t >> 1;
    const int shalf = t & 1;
    const float* Xp = X  + (size_t)(m0 + srow) * KDIM + shalf * 16;
    const int*   Wp = Wq + (size_t)(n0 + srow) * KDIM + shalf * 16;

    f32x4 acc[4][4];
    #pragma unroll
    for (int i = 0; i < 4; ++i)
        #pragma unroll
        for (int j = 0; j < 4; ++j)
            acc[i][j] = (f32x4){0.f, 0.f, 0.f, 0.f};

    const int fr = lane & 15;
    const int fs = lane >> 4;

    f32x4 ar[4];
    i32x4 br[4];
    #pragma unroll
    for (int p = 0; p < 4; ++p) {
        ar[p] = *(const f32x4*)(Xp + p * 4);
        br[p] = *(const i32x4*)(Wp + p * 4);
    }

    const int wbase = srow * 4;
    const int wswz  = (srow >> 1) & 3;
    const int ws0   = (shalf * 2)     ^ wswz;
    const int ws1   = (shalf * 2 + 1) ^ wswz;

    for (int kt = 0; kt < KDIM / 32; ++kt) {
        __syncthreads();
        {
            s16x8 v0, v1;
            #pragma unroll
            for (int q = 0; q < 8; ++q) v0[q] = f2bf(ar[q >> 2][q & 3]);
            #pragma unroll
            for (int q = 0; q < 8; ++q) v1[q] = f2bf(ar[2 + (q >> 2)][q & 3]);
            As[wbase + ws0] = v0;
            As[wbase + ws1] = v1;
            s16x8 u0, u1;
            #pragma unroll
            for (int q = 0; q < 8; ++q) u0[q] = f2bf((float)br[q >> 2][q & 3]);
            #pragma unroll
            for (int q = 0; q < 8; ++q) u1[q] = f2bf((float)br[2 + (q >> 2)][q & 3]);
            Bs[wbase + ws0] = u0;
            Bs[wbase + ws1] = u1;
        }
        __syncthreads();

        if (kt + 1 < KDIM / 32) {
            const float* Xn = Xp + (size_t)(kt + 1) * 32;
            const int*   Wn = Wp + (size_t)(kt + 1) * 32;
            #pragma unroll
            for (int p = 0; p < 4; ++p) {
                ar[p] = *(const f32x4*)(Xn + p * 4);
                br[p] = *(const i32x4*)(Wn + p * 4);
            }
        }

        s16x8 af[4], bq[4];
        #pragma unroll
        for (int i = 0; i < 4; ++i) {
            int row = wr * 64 + i * 16 + fr;
            af[i] = As[row * 4 + (fs ^ ((row >> 1) & 3))];
        }
        #pragma unroll
        for (int j = 0; j < 4; ++j) {
            int col = wc * 64 + j * 16 + fr;
            bq[j] = Bs[col * 4 + (fs ^ ((col >> 1) & 3))];
        }
        #pragma unroll
        for (int i = 0; i < 4; ++i)
            #pragma unroll
            for (int j = 0; j < 4; ++j)
                acc[i][j] = __builtin_amdgcn_mfma_f32_16x16x32_bf16(
                    af[i], bq[j], acc[i][j], 0, 0, 0);
    }

    const float scale = scale_p[0];
    #pragma unroll
    for (int j = 0; j < 4; ++j) {
        const int c  = n0 + wc * 64 + j * 16 + fr;
        const float bj = bias[c];
        #pragma unroll
        for (int i = 0; i < 4; ++i) {
            const int r0 = m0 + wr * 64 + i * 16 + fs * 4;
            float* op = Out + (size_t)r0 * NDIM + c;
            #pragma unroll
            for (int q = 0; q < 4; ++q)
                op[(size_t)q * NDIM] = acc[i][j][q] * scale + bj;
        }
    }
}

extern "C" void kernel_launch(void* const* d_in, const int* in_sizes, int n_in,
                              void* d_out, int out_size, void* d_ws, size_t ws_size,
                              hipStream_t stream) {
    const float* X     = (const float*)d_in[0];
    const int*   Wq    = (const int*)d_in[1];   // int8 widened to int32 by harness
    const float* scale = (const float*)d_in[2];
    const float* bias  = (const float*)d_in[3];
    float*       Out   = (float*)d_out;

    const size_t xqB = (size_t)MDIM * KDIM;          // 33.5 MB
    const size_t wqB = (size_t)NDIM * KDIM;          // 67 MB
    const size_t sxB = (size_t)MDIM * sizeof(float); // 32 KB
    if (ws_size >= xqB + wqB + sxB) {
        char*  Xq  = (char*)d_ws;
        char*  Wq8 = (char*)d_ws + xqB;
        float* sx  = (float*)((char*)d_ws + xqB + wqB);
        hipLaunchKernelGGL(quant_x, dim3(MDIM), dim3(256), 0, stream, X, Xq, sx);
        hipLaunchKernelGGL(pack_w, dim3(2048), dim3(256), 0, stream,
                           Wq, Wq8, NDIM * KDIM / 16);
        hipLaunchKernelGGL(sl_gemm_i8s, dim3(8192), dim3(256), 0, stream,
                           Xq, Wq8, sx, scale, bias, Out);
    } else {
        hipLaunchKernelGGL(sl_gemm_fb, dim3(8192), dim3(256), 0, stream,
                           X, Wq, scale, bias, Out);
    }
}